// Round 6
// baseline (539.568 us; speedup 1.0000x reference)
//
#include <hip/hip_runtime.h>
#include <stdint.h>

// hipcc defaults to -ffp-contract=fast and HIP's __f*_rn intrinsics are plain
// ops, so FMA contraction was silently changing IoU by ~1 ulp vs numpy and
// flipping discrete selections (pos/neg threshold + rank boundaries).
// Force scalar IEEE f32 per-op semantics for everything selection-relevant.
#pragma clang fp contract(off)

#define BATCH 32
#define NROI  12000
#define NGT   200
#define BGCLS 20
#define ROIBS 256
#define NPOS  64
#define VPT   47   // ceil(NROI/256) values owned per thread; n = tid + 256*j

// IoU of one roi vs all gts + masked argmax (np.argmax: FIRST max wins).
// Must equal numpy f32 bitwise: left-to-right ((ar+ag)-inter)+1e-8, IEEE div,
// no FMA contraction (pragma above + per-function pragma).
__device__ __forceinline__ void roi_maxiou(const float* sy1, const float* sx1,
                                           const float* sy2, const float* sx2,
                                           const float* sarea, const int* scls,
                                           float ry1, float rx1, float ry2, float rx2,
                                           float& best, int& bg) {
#pragma clang fp contract(off)
  float ar = (ry2 - ry1) * (rx2 - rx1);
  best = -2.0f; bg = 0;
  for (int g = 0; g < NGT; ++g) {
    float yy1 = fmaxf(ry1, sy1[g]);
    float xx1 = fmaxf(rx1, sx1[g]);
    float yy2 = fminf(ry2, sy2[g]);
    float xx2 = fminf(rx2, sx2[g]);
    float inter = fmaxf(yy2 - yy1, 0.0f) * fmaxf(xx2 - xx1, 0.0f);
    float den = ((ar + sarea[g]) - inter) + 1e-8f;
    float iou = inter / den;
    if (scls[g] >= BGCLS) iou = -1.0f;            // where(valid, iou, -1)
    if (iou > best) { best = iou; bg = g; }       // strict > == first-index argmax
  }
}

__device__ __forceinline__ void load_gt(float* sy1, float* sx1, float* sy2, float* sx2,
                                        float* sarea, int* scls,
                                        const float* gtb, const int* gtc, int b, int tid) {
#pragma clang fp contract(off)
  for (int g = tid; g < NGT; g += 256) {
    const float4 p = *(const float4*)(gtb + ((size_t)b * NGT + g) * 4);
    sy1[g] = p.x; sx1[g] = p.y; sy2[g] = p.z; sx2[g] = p.w;
    sarea[g] = (p.z - p.x) * (p.w - p.y);
    scls[g] = gtc[(size_t)b * NGT + g];
  }
}

__global__ __launch_bounds__(256) void k_ioumax(const float* __restrict__ rois,
                                                const int* __restrict__ gtc,
                                                const float* __restrict__ gtb,
                                                float* __restrict__ max_iou) {
  __shared__ float sy1[NGT], sx1[NGT], sy2[NGT], sx2[NGT], sarea[NGT];
  __shared__ int scls[NGT];
  int b = blockIdx.y;
  load_gt(sy1, sx1, sy2, sx2, sarea, scls, gtb, gtc, b, threadIdx.x);
  __syncthreads();
  int n = blockIdx.x * 256 + threadIdx.x;
  if (n >= NROI) return;
  const float4 r = *(const float4*)(rois + ((size_t)b * NROI + n) * 4);
  float best; int bg;
  roi_maxiou(sy1, sx1, sy2, sx2, sarea, scls, r.x, r.y, r.z, r.w, best, bg);
  max_iou[(size_t)b * NROI + n] = best;
}

template <bool USE_WS>
__global__ __launch_bounds__(256) void k_sel(const float* __restrict__ rois,
                                             const int* __restrict__ gtc,
                                             const float* __restrict__ gtb,
                                             const float* __restrict__ max_iou,
                                             float* __restrict__ out) {
#pragma clang fp contract(off)
  __shared__ float sy1[NGT], sx1[NGT], sy2[NGT], sx2[NGT], sarea[NGT];
  __shared__ int scls[NGT];
  __shared__ unsigned long long wred[4];
  __shared__ int sel_r[ROIBS];
  __shared__ int sel_p[ROIBS];
  const int b = blockIdx.x;
  const int tid = threadIdx.x;
  load_gt(sy1, sx1, sy2, sx2, sarea, scls, gtb, gtc, b, tid);
  __syncthreads();

  // ---- per-thread register-resident max_iou values (static indexing only) ----
  float v[VPT];
  if constexpr (USE_WS) {
#pragma unroll
    for (int j = 0; j < VPT; ++j) {
      int n = tid + (j << 8);
      v[j] = (n < NROI) ? max_iou[(size_t)b * NROI + n] : -3.0f;
    }
  } else {
    __shared__ float val[NROI];
    for (int n = tid; n < NROI; n += 256) {
      const float4 r = *(const float4*)(rois + ((size_t)b * NROI + n) * 4);
      float best; int bg;
      roi_maxiou(sy1, sx1, sy2, sx2, sarea, scls, r.x, r.y, r.z, r.w, best, bg);
      val[n] = best;
    }
    __syncthreads();
#pragma unroll
    for (int j = 0; j < VPT; ++j) {
      int n = tid + (j << 8);
      v[j] = (n < NROI) ? val[n] : -3.0f;
    }
  }

  unsigned long long killed = 0ull;  // bit j: owned element j already selected

  // Block argmax of (value desc, index ASC on ties) over live elems >= lo —
  // matches jax.lax.top_k / stable-argsort numpy transliteration.
  // Key: bits(v)<<32 | (0x7fffffff - n); v > 0 => bits monotone; 0 == "none".
  auto pick = [&](float lo) -> unsigned long long {
    float bv = -1.0f; int bn = 0x7fffffff;
#pragma unroll
    for (int j = 0; j < VPT; ++j) {              // ascending j; strict > keeps FIRST max
      int n = tid + (j << 8);
      if (n < NROI && !(killed & (1ull << j)) && v[j] >= lo && v[j] > bv) {
        bv = v[j]; bn = n;                       // lowest n among equals
      }
    }
    unsigned long long key = (bv >= lo)
        ? (((unsigned long long)__float_as_uint(bv) << 32) | (unsigned)(0x7fffffff - bn))
        : 0ull;
    for (int off = 1; off < 64; off <<= 1) {
      unsigned hi = __shfl_xor((unsigned)(key >> 32), off, 64);
      unsigned lo32 = __shfl_xor((unsigned)(key & 0xffffffffu), off, 64);
      unsigned long long o = ((unsigned long long)hi << 32) | lo32;
      if (o > key) key = o;
    }
    if ((tid & 63) == 0) wred[tid >> 6] = key;
    __syncthreads();
    unsigned long long m = wred[0];
    for (int w = 1; w < 4; ++w) if (wred[w] > m) m = wred[w];
    __syncthreads();                             // protect wred reuse next pick
    return m;
  };

  // ---- positives: iou >= 0.5, by (iou desc, index asc); emitted in pick
  //      order (f32 prio ties {0..32}/{33..63} collapse, stable top_k keeps
  //      slot order => emission order == pick order) ----
  int P = 0;
#pragma unroll 1
  for (int k = 0; k < NPOS; ++k) {
    unsigned long long key = pick(0.5f);
    if (key == 0ull) break;                      // uniform: none left
    int n = 0x7fffffff - (int)(key & 0xffffffffu);
    if (tid == 0) { sel_r[k] = n; sel_p[k] = 1; }
    if ((n & 255) == tid) killed |= 1ull << (n >> 8);
    ++P;
  }

  // ---- negative key: f32(v + 2.0) (the +2.0 ROUNDING merges nearby ious;
  //      merged ties break by ASC index via pick) ----
#pragma unroll
  for (int j = 0; j < VPT; ++j) {
    int n = tid + (j << 8);
    bool isneg = (n < NROI) && !(killed & (1ull << j)) && v[j] >= 0.0f && v[j] < 0.5f;
    v[j] = isneg ? (v[j] + 2.0f) : -3.0f;
  }

  // ---- negatives fill slots P..255 in pick order (1e6-rN prios distinct) ----
#pragma unroll 1
  for (int k = P; k < ROIBS; ++k) {
    unsigned long long key = pick(1.0f);
    int n = key ? (0x7fffffff - (int)(key & 0xffffffffu)) : 0;
    if (tid == 0) { sel_r[k] = n; sel_p[k] = 0; }
    if (key && (n & 255) == tid) killed |= 1ull << (n >> 8);
  }
  __syncthreads();

  // ---- emit (f32 output): one thread per slot; covers all of d_out ----
  {
    int k = tid;
    int r = sel_r[k];
    int isp = sel_p[k];
    const float4 rv = *(const float4*)(rois + ((size_t)b * NROI + r) * 4);
    float ry1 = rv.x, rx1 = rv.y, ry2 = rv.z, rx2 = rv.w;
    float best; int bg;
    roi_maxiou(sy1, sx1, sy2, sx2, sarea, scls, ry1, rx1, ry2, rx2, best, bg);
    int label = isp ? scls[bg] : BGCLS;

    float* out1 = out;                                    // [B,256,4]
    float* out2 = out + (size_t)BATCH * ROIBS * 4;        // [B,256,21]
    float* out3 = out + (size_t)BATCH * ROIBS * 25;       // [B,256,160]
    size_t row = (size_t)b * ROIBS + k;

    *(float4*)(out1 + row * 4) = rv;                      // bit-exact roi copy

    float* o2 = out2 + row * 21;
    for (int c = 0; c <= BGCLS; ++c) o2[c] = (c == label) ? 1.0f : 0.0f;

    float t0 = 0.f, t1 = 0.f, t2 = 0.f, t3 = 0.f;
    if (isp) {
      const float eps = 1e-6f;
      float gy1 = sy1[bg], gx1 = sx1[bg], gy2 = sy2[bg], gx2 = sx2[bg];
      float rh = ry2 - ry1, rw = rx2 - rx1;
      float rcy = ry1 + rh * 0.5f, rcx = rx1 + rw * 0.5f;
      float gh = gy2 - gy1, gw = gx2 - gx1;
      float gcy = gy1 + gh * 0.5f, gcx = gx1 + gw * 0.5f;
      t0 = ((gcx - rcx) / (rw + eps)) * 10.0f;
      t1 = ((gcy - rcy) / (rh + eps)) * 10.0f;
      t2 = logf(fmaxf(gw, eps) / (rw + eps)) * 5.0f;
      t3 = logf(fmaxf(gh, eps) / (rh + eps)) * 5.0f;
    }
    int m0 = label * 4;                          // meaningful only when isp
    float* o3 = out3 + row * 160;
    for (int c = 0; c < 40; ++c) {               // 40 x 16B aligned vector stores
      float4 w = make_float4(0.f, 0.f, 0.f, 0.f);
      if (isp) {
        float* wp = &w.x;
#pragma unroll
        for (int jj = 0; jj < 4; ++jj) {
          int e = c * 4 + jj;
          float x = 0.f;
          if (e >= m0 && e < m0 + 4) x = 1.0f;   // mask4 half [0,80)
          int d = e - 80 - m0;                   // deltas half [80,160)
          if (d == 0) x = t0; else if (d == 1) x = t1;
          else if (d == 2) x = t2; else if (d == 3) x = t3;
          wp[jj] = x;
        }
      }
      *(float4*)(o3 + c * 4) = w;
    }
  }
}

extern "C" void kernel_launch(void* const* d_in, const int* in_sizes, int n_in,
                              void* d_out, int out_size, void* d_ws, size_t ws_size,
                              hipStream_t stream) {
  const float* rois = (const float*)d_in[0];   // [32,12000,4] f32
  const int*   gtc  = (const int*)d_in[1];     // [32,200] i32
  const float* gtb  = (const float*)d_in[2];   // [32,200,4] f32
  float*       out  = (float*)d_out;           // f32, 32*256*185 elements

  size_t need = (size_t)BATCH * NROI * sizeof(float);
  if (d_ws && ws_size >= need) {
    float* mi = (float*)d_ws;
    k_ioumax<<<dim3((NROI + 255) / 256, BATCH), 256, 0, stream>>>(rois, gtc, gtb, mi);
    k_sel<true><<<BATCH, 256, 0, stream>>>(rois, gtc, gtb, mi, out);
  } else {
    k_sel<false><<<BATCH, 256, 0, stream>>>(rois, gtc, gtb, nullptr, out);
  }
}

// Round 7
// 146.092 us; speedup vs baseline: 3.6933x; 3.6933x over previous
//
#include <hip/hip_runtime.h>
#include <stdint.h>

// hipcc defaults to -ffp-contract=fast; FMA fusion perturbs IoU by ~1 ulp vs
// numpy and flips discrete selections (R3-R6 ladder). Force per-op IEEE f32.
#pragma clang fp contract(off)

#define BATCH 32
#define NROI  12000
#define NGT   200
#define BGCLS 20
#define ROIBS 256
#define NPOS  64
#define NBIN  1024
#define CAP   1024

// IoU of one roi vs all gts + masked argmax (first-max wins). Bit-exact vs
// numpy f32: left-to-right ((ar+ag)-inter)+1e-8, IEEE div, no contraction.
// Invalid gts (cls>=BG) skipped: equivalent to iou=-1 entries given
// best init -1/bg=0 (valid ious >= 0 always beat them; all-invalid -> (-1,0)).
__device__ __forceinline__ void roi_maxiou(const float4* sbox, const float* sarea,
                                           const int* scls,
                                           float ry1, float rx1, float ry2, float rx2,
                                           float& best, int& bg) {
#pragma clang fp contract(off)
  float ar = (ry2 - ry1) * (rx2 - rx1);
  best = -1.0f; bg = 0;
  for (int g = 0; g < NGT; ++g) {
    if (scls[g] < BGCLS) {                       // wave-uniform branch
      float4 q = sbox[g];
      float yy1 = fmaxf(ry1, q.x);
      float xx1 = fmaxf(rx1, q.y);
      float yy2 = fminf(ry2, q.z);
      float xx2 = fminf(rx2, q.w);
      float inter = fmaxf(yy2 - yy1, 0.0f) * fmaxf(xx2 - xx1, 0.0f);
      float den = ((ar + sarea[g]) - inter) + 1e-8f;
      float iou = inter / den;
      if (iou > best) { best = iou; bg = g; }    // strict > == first-index argmax
    }
  }
}

__global__ __launch_bounds__(256) void k_ioumax(const float* __restrict__ rois,
                                                const int* __restrict__ gtc,
                                                const float* __restrict__ gtb,
                                                float* __restrict__ max_iou) {
  __shared__ float4 sbox[NGT];
  __shared__ float sarea[NGT];
  __shared__ int scls[NGT];
  int b = blockIdx.y;
  for (int g = threadIdx.x; g < NGT; g += 256) {
    float4 p = *(const float4*)(gtb + ((size_t)b * NGT + g) * 4);
    sbox[g] = p;
    sarea[g] = (p.z - p.x) * (p.w - p.y);
    scls[g] = gtc[(size_t)b * NGT + g];
  }
  __syncthreads();
  int n = blockIdx.x * 256 + threadIdx.x;
  if (n >= NROI) return;
  const float4 r = *(const float4*)(rois + ((size_t)b * NROI + n) * 4);
  float best; int bg;
  roi_maxiou(sbox, sarea, scls, r.x, r.y, r.z, r.w, best, bg);
  max_iou[(size_t)b * NROI + n] = best;
}

// One block per image. Selection via histogram-prune + bitonic sort:
//   key = bits(f32 value)<<32 | (0x7fffffff - n)  -> desc sort == (val desc,
//   index asc) == jax stable top_k. pos (v>=0.5) and neg (0<=v<0.5) are
//   disjoint, so two independent top-k rounds reproduce the reference's
//   prio-merge exactly (pos block slots 0..P-1 in order, then negs in order).
template <bool USE_WS>
__global__ __launch_bounds__(256) void k_sel(const float* __restrict__ rois,
                                             const int* __restrict__ gtc,
                                             const float* __restrict__ gtb,
                                             const float* __restrict__ max_iou,
                                             float* __restrict__ out) {
#pragma clang fp contract(off)
  __shared__ float4 sbox[NGT];
  __shared__ float sarea[NGT];
  __shared__ int scls[NGT];
  __shared__ float val[NROI];
  __shared__ unsigned long long list[CAP];
  __shared__ int hist[NBIN];
  __shared__ int part[256];
  __shared__ int scnt, sT;
  const int b = blockIdx.x;
  const int tid = threadIdx.x;

  for (int g = tid; g < NGT; g += 256) {
    float4 p = *(const float4*)(gtb + ((size_t)b * NGT + g) * 4);
    sbox[g] = p;
    sarea[g] = (p.z - p.x) * (p.w - p.y);
    scls[g] = gtc[(size_t)b * NGT + g];
  }
  __syncthreads();

  if constexpr (USE_WS) {
    for (int n = tid; n < NROI; n += 256) val[n] = max_iou[(size_t)b * NROI + n];
  } else {
    for (int n = tid; n < NROI; n += 256) {
      const float4 r = *(const float4*)(rois + ((size_t)b * NROI + n) * 4);
      float best; int bg;
      roi_maxiou(sbox, sarea, scls, r.x, r.y, r.z, r.w, best, bg);
      val[n] = best;
    }
  }
  __syncthreads();

  // threshold bin T = smallest bin with suffix-count >= need (ties cannot
  // straddle a bin: equal keys -> equal bin). total < need -> T=0 (take all).
  auto find_T = [&](int need) {
    part[tid] = hist[4 * tid] + hist[4 * tid + 1] + hist[4 * tid + 2] + hist[4 * tid + 3];
    __syncthreads();
    if (tid == 0) {
      int acc = 0, T = 0; bool found = false;
      for (int g = 255; g >= 0 && !found; --g) {
        int na = acc + part[g];
        if (na >= need) {
          int a2 = acc;
          for (int bb = 4 * g + 3; bb >= 4 * g; --bb) {
            a2 += hist[bb];
            if (a2 >= need) { T = bb; break; }
          }
          found = true;
        }
        acc = na;
      }
      sT = found ? T : 0;
    }
    __syncthreads();
  };

  // descending bitonic sort of list[0..m), m power of 2, pad entries == 0.
  auto bitonic = [&](int m) {
    for (int ksz = 2; ksz <= m; ksz <<= 1)
      for (int j = ksz >> 1; j > 0; j >>= 1) {
        for (int i = tid; i < m; i += 256) {
          int l = i ^ j;
          if (l > i) {
            unsigned long long a = list[i], c = list[l];
            bool up = ((i & ksz) == 0);
            if (up ? (a < c) : (a > c)) { list[i] = c; list[l] = a; }
          }
        }
        __syncthreads();
      }
  };

  // ===== positives: top-64 of v >= 0.5, (v desc, index asc) =====
  for (int i = tid; i < NBIN; i += 256) hist[i] = 0;
  if (tid == 0) scnt = 0;
  __syncthreads();
  for (int n = tid; n < NROI; n += 256) {
    float v = val[n];
    if (v >= 0.5f) {
      int bin = min((int)((__float_as_uint(v) - 0x3F000000u) >> 13), NBIN - 1);
      atomicAdd(&hist[bin], 1);
    }
  }
  __syncthreads();
  find_T(NPOS);
  {
    int T = sT;
    for (int n = tid; n < NROI; n += 256) {
      float v = val[n];
      if (v >= 0.5f) {
        unsigned kh = __float_as_uint(v);
        int bin = min((int)((kh - 0x3F000000u) >> 13), NBIN - 1);
        if (bin >= T) {
          int idx = atomicAdd(&scnt, 1);
          if (idx < CAP)
            list[idx] = ((unsigned long long)kh << 32) | (unsigned)(0x7fffffff - n);
        }
      }
    }
  }
  __syncthreads();
  int cnt = min(scnt, CAP);
  int m = 1; while (m < cnt) m <<= 1;
  for (int i = cnt + tid; i < m; i += 256) list[i] = 0ull;
  __syncthreads();
  bitonic(m);
  const int P = min(cnt, NPOS);
  int myR = 0, myP = 0;
  if (tid < P) { myR = 0x7fffffff - (int)(list[tid] & 0xffffffffu); myP = 1; }
  __syncthreads();                               // before list/hist reuse

  // ===== negatives: top-(256-P) of 0 <= v < 0.5 by f32(v+2.0) key =====
  // (the +2.0 ROUNDING merges nearby ious; merged ties break asc-index)
  const int need = ROIBS - P;
  for (int i = tid; i < NBIN; i += 256) hist[i] = 0;
  if (tid == 0) scnt = 0;
  __syncthreads();
  for (int n = tid; n < NROI; n += 256) {
    float v = val[n];
    if (v >= 0.0f && v < 0.5f) {
      float kv = v + 2.0f;                       // IEEE RNE, no contraction
      int bin = min((int)((__float_as_uint(kv) - 0x40000000u) >> 11), NBIN - 1);
      atomicAdd(&hist[bin], 1);
    }
  }
  __syncthreads();
  find_T(need);
  {
    int T = sT;
    for (int n = tid; n < NROI; n += 256) {
      float v = val[n];
      if (v >= 0.0f && v < 0.5f) {
        unsigned kh = __float_as_uint(v + 2.0f);
        int bin = min((int)((kh - 0x40000000u) >> 11), NBIN - 1);
        if (bin >= T) {
          int idx = atomicAdd(&scnt, 1);
          if (idx < CAP)
            list[idx] = ((unsigned long long)kh << 32) | (unsigned)(0x7fffffff - n);
        }
      }
    }
  }
  __syncthreads();
  int cnt2 = min(scnt, CAP);
  int m2 = 1; while (m2 < cnt2) m2 <<= 1;
  for (int i = cnt2 + tid; i < m2; i += 256) list[i] = 0ull;
  __syncthreads();
  bitonic(m2);
  if (!myP) {
    int i2 = tid - P;
    myR = (i2 >= 0 && i2 < cnt2) ? (0x7fffffff - (int)(list[i2] & 0xffffffffu)) : 0;
  }

  // ===== emit (f32 output): thread tid == slot; covers all of d_out =====
  {
    int r = myR;
    int isp = myP;
    const float4 rv = *(const float4*)(rois + ((size_t)b * NROI + r) * 4);
    float ry1 = rv.x, rx1 = rv.y, ry2 = rv.z, rx2 = rv.w;
    float best; int bg;
    roi_maxiou(sbox, sarea, scls, ry1, rx1, ry2, rx2, best, bg);
    int label = isp ? scls[bg] : BGCLS;

    float* out1 = out;                                    // [B,256,4]
    float* out2 = out + (size_t)BATCH * ROIBS * 4;        // [B,256,21]
    float* out3 = out + (size_t)BATCH * ROIBS * 25;       // [B,256,160]
    size_t row = (size_t)b * ROIBS + tid;

    *(float4*)(out1 + row * 4) = rv;                      // bit-exact roi copy

    float* o2 = out2 + row * 21;
    for (int c = 0; c <= BGCLS; ++c) o2[c] = (c == label) ? 1.0f : 0.0f;

    float t0 = 0.f, t1 = 0.f, t2 = 0.f, t3 = 0.f;
    if (isp) {
      const float eps = 1e-6f;
      float4 q = sbox[bg];
      float gy1 = q.x, gx1 = q.y, gy2 = q.z, gx2 = q.w;
      float rh = ry2 - ry1, rw = rx2 - rx1;
      float rcy = ry1 + rh * 0.5f, rcx = rx1 + rw * 0.5f;
      float gh = gy2 - gy1, gw = gx2 - gx1;
      float gcy = gy1 + gh * 0.5f, gcx = gx1 + gw * 0.5f;
      t0 = ((gcx - rcx) / (rw + eps)) * 10.0f;
      t1 = ((gcy - rcy) / (rh + eps)) * 10.0f;
      t2 = logf(fmaxf(gw, eps) / (rw + eps)) * 5.0f;
      t3 = logf(fmaxf(gh, eps) / (rh + eps)) * 5.0f;
    }
    int m0 = label * 4;                          // meaningful only when isp
    float* o3 = out3 + row * 160;
    for (int c = 0; c < 40; ++c) {               // 40 x 16B aligned vector stores
      float4 w = make_float4(0.f, 0.f, 0.f, 0.f);
      if (isp) {
        float* wp = &w.x;
#pragma unroll
        for (int jj = 0; jj < 4; ++jj) {
          int e = c * 4 + jj;
          float x = 0.f;
          if (e >= m0 && e < m0 + 4) x = 1.0f;   // mask4 half [0,80)
          int d = e - 80 - m0;                   // deltas half [80,160)
          if (d == 0) x = t0; else if (d == 1) x = t1;
          else if (d == 2) x = t2; else if (d == 3) x = t3;
          wp[jj] = x;
        }
      }
      *(float4*)(o3 + c * 4) = w;
    }
  }
}

extern "C" void kernel_launch(void* const* d_in, const int* in_sizes, int n_in,
                              void* d_out, int out_size, void* d_ws, size_t ws_size,
                              hipStream_t stream) {
  const float* rois = (const float*)d_in[0];   // [32,12000,4] f32
  const int*   gtc  = (const int*)d_in[1];     // [32,200] i32
  const float* gtb  = (const float*)d_in[2];   // [32,200,4] f32
  float*       out  = (float*)d_out;           // f32, 32*256*185 elements

  size_t need = (size_t)BATCH * NROI * sizeof(float);
  if (d_ws && ws_size >= need) {
    float* mi = (float*)d_ws;
    k_ioumax<<<dim3((NROI + 255) / 256, BATCH), 256, 0, stream>>>(rois, gtc, gtb, mi);
    k_sel<true><<<BATCH, 256, 0, stream>>>(rois, gtc, gtb, mi, out);
  } else {
    k_sel<false><<<BATCH, 256, 0, stream>>>(rois, gtc, gtb, nullptr, out);
  }
}

// Round 8
// 116.361 us; speedup vs baseline: 4.6370x; 1.2555x over previous
//
#include <hip/hip_runtime.h>
#include <stdint.h>

// hipcc defaults to -ffp-contract=fast; FMA fusion perturbs IoU by ~1 ulp vs
// numpy and flips discrete selections (R3-R6 ladder). Force per-op IEEE f32.
#pragma clang fp contract(off)

#define BATCH 32
#define NROI  12000
#define NGT   200
#define BGCLS 20
#define ROIBS 256
#define NPOS  64
#define NBIN  1024
#define CAP   1024

// Ballot-compacted valid-GT staging. Compaction preserves original gt order,
// so first-max argmax over the compacted list == reference masked argmax.
__device__ __forceinline__ void stage_gt(float4* cbox, float* carea, int* ccls,
                                         int* snv, int* wtmp,
                                         const float* gtb, const int* gtc, int b) {
  int tid = threadIdx.x;
  bool valid = false; float4 p = make_float4(0.f, 0.f, 0.f, 0.f); int cls = BGCLS;
  if (tid < NGT) {
    p = *(const float4*)(gtb + ((size_t)b * NGT + tid) * 4);
    cls = gtc[(size_t)b * NGT + tid];
    valid = (cls < BGCLS);
  }
  unsigned long long m = __ballot(valid);
  int w = tid >> 6;
  if ((tid & 63) == 0) wtmp[w] = __popcll(m);
  __syncthreads();
  if (tid == 0) *snv = wtmp[0] + wtmp[1] + wtmp[2] + wtmp[3];
  if (valid) {
    int off = 0;
    for (int i = 0; i < w; ++i) off += wtmp[i];
    int pos = off + __popcll(m & ((1ull << (tid & 63)) - 1ull));
    cbox[pos] = p;
    carea[pos] = (p.z - p.x) * (p.w - p.y);
    ccls[pos] = cls;
  }
  __syncthreads();
}

// IoU vs compacted gts + first-max argmax. Bit-exact numpy f32:
// left-to-right ((ar+ag)-inter)+1e-8, IEEE div, no contraction.
__device__ __forceinline__ void roi_maxiou(const float4* cbox, const float* carea,
                                           int nv, float ry1, float rx1,
                                           float ry2, float rx2,
                                           float& best, int& bj) {
#pragma clang fp contract(off)
  float ar = (ry2 - ry1) * (rx2 - rx1);
  best = -1.0f; bj = 0;
  for (int j = 0; j < nv; ++j) {
    float4 q = cbox[j];
    float yy1 = fmaxf(ry1, q.x);
    float xx1 = fmaxf(rx1, q.y);
    float yy2 = fminf(ry2, q.z);
    float xx2 = fminf(rx2, q.w);
    float inter = fmaxf(yy2 - yy1, 0.0f) * fmaxf(xx2 - xx1, 0.0f);
    float den = ((ar + carea[j]) - inter) + 1e-8f;
    float iou = inter / den;
    if (iou > best) { best = iou; bj = j; }      // strict > == first-index argmax
  }
}

__global__ __launch_bounds__(256) void k_ioumax(const float* __restrict__ rois,
                                                const int* __restrict__ gtc,
                                                const float* __restrict__ gtb,
                                                float* __restrict__ max_iou) {
  __shared__ float4 cbox[NGT];
  __shared__ float carea[NGT];
  __shared__ int ccls[NGT];
  __shared__ int snv, wtmp[4];
  int b = blockIdx.y;
  stage_gt(cbox, carea, ccls, &snv, wtmp, gtb, gtc, b);
  int n = blockIdx.x * 256 + threadIdx.x;
  if (n >= NROI) return;
  const float4 r = *(const float4*)(rois + ((size_t)b * NROI + n) * 4);
  float best; int bj;
  roi_maxiou(cbox, carea, snv, r.x, r.y, r.z, r.w, best, bj);
  max_iou[(size_t)b * NROI + n] = best;
}

// One block per image. Two top-k phases (pos v>=0.5 by bits(v); neg 0<=v<0.5
// by bits(f32(v+2.0)) -- the +2.0 ROUNDING merges nearby ious, merged ties
// break asc-index). key = kh<<32 | (0x7fffffff-n): desc == (val desc, idx asc)
// == jax stable top_k. Histogram-prune (sharded x4, parallel suffix-scan
// threshold) + rank selection (keys unique) -- no serial lane-0 loops.
template <bool USE_WS>
__global__ __launch_bounds__(256) void k_sel(const float* __restrict__ rois,
                                             const int* __restrict__ gtc,
                                             const float* __restrict__ gtb,
                                             const float* __restrict__ max_iou,
                                             float* __restrict__ out) {
#pragma clang fp contract(off)
  __shared__ float4 cbox[NGT];
  __shared__ float carea[NGT];
  __shared__ int ccls[NGT];
  __shared__ int snv, wtmp[4];
  __shared__ float val[NROI];
  __shared__ unsigned long long list[CAP];
  __shared__ int h4[4][NBIN];
  __shared__ int ss[256];
  __shared__ int sel_r[ROIBS];
  __shared__ int scnt, sT;
  const int b = blockIdx.x;
  const int tid = threadIdx.x;

  stage_gt(cbox, carea, ccls, &snv, wtmp, gtb, gtc, b);
  const int nv = snv;
  sel_r[tid] = 0;                                // default roi 0 (slot underflow)

  if constexpr (USE_WS) {
    for (int n = tid; n < NROI; n += 256) val[n] = max_iou[(size_t)b * NROI + n];
  } else {
    for (int n = tid; n < NROI; n += 256) {
      const float4 r = *(const float4*)(rois + ((size_t)b * NROI + n) * 4);
      float best; int bj;
      roi_maxiou(cbox, carea, nv, r.x, r.y, r.z, r.w, best, bj);
      val[n] = best;
    }
  }
  __syncthreads();

  // One selection phase: filter [lo,hi), key kh = bits(isPos ? v : v+2.0f),
  // bin = (kh-base)>>shift (monotone in key; equal keys -> equal bin).
  // T = highest bin with suffix-count >= need. Candidates (bin>=T) ranked by
  // key desc; rank < limit -> slot slotBase+rank. Returns limit (# filled).
  auto phase = [&](bool isPos, int need, unsigned base, int shift,
                   float lo, float hi, int slotBase) -> int {
    for (int i = tid; i < 4 * NBIN; i += 256) ((int*)h4)[i] = 0;
    if (tid == 0) { scnt = 0; sT = 0; }
    __syncthreads();
    const int w = tid >> 6;
    for (int n = tid; n < NROI; n += 256) {
      float v = val[n];
      if (v >= lo && v < hi) {
        float kv = isPos ? v : (v + 2.0f);       // IEEE RNE, no contraction
        int bin = min((int)((__float_as_uint(kv) - base) >> shift), NBIN - 1);
        atomicAdd(&h4[w][bin], 1);
      }
    }
    __syncthreads();
    // per-thread bin sums (bins 4t..4t+3) across the 4 shards
    int s0 = h4[0][4*tid+0] + h4[1][4*tid+0] + h4[2][4*tid+0] + h4[3][4*tid+0];
    int s1 = h4[0][4*tid+1] + h4[1][4*tid+1] + h4[2][4*tid+1] + h4[3][4*tid+1];
    int s2 = h4[0][4*tid+2] + h4[1][4*tid+2] + h4[2][4*tid+2] + h4[3][4*tid+2];
    int s3 = h4[0][4*tid+3] + h4[1][4*tid+3] + h4[2][4*tid+3] + h4[3][4*tid+3];
    ss[tid] = s0 + s1 + s2 + s3;
    __syncthreads();
    // Hillis-Steele suffix scan: ss[t] = sum_{t'>=t} part[t']
    for (int off = 1; off < 256; off <<= 1) {
      int a = (tid + off < 256) ? ss[tid + off] : 0;
      __syncthreads();
      ss[tid] += a;
      __syncthreads();
    }
    // locate unique crossing suffix(bin)>=need > suffix(bin+1)
    {
      int sfx = (tid + 1 < 256) ? ss[tid + 1] : 0;   // suffix of bin 4t+4
      int sb[4] = {s0, s1, s2, s3};
      for (int k = 3; k >= 0; --k) {
        int cur = sfx + sb[k];
        if (cur >= need && sfx < need) sT = 4 * tid + k;  // single writer
        sfx = cur;
      }
    }
    __syncthreads();
    const int T = sT;                            // 0 if total < need (take all)
    for (int n = tid; n < NROI; n += 256) {
      float v = val[n];
      if (v >= lo && v < hi) {
        unsigned kh = __float_as_uint(isPos ? v : (v + 2.0f));
        int bin = min((int)((kh - base) >> shift), NBIN - 1);
        if (bin >= T) {
          int idx = atomicAdd(&scnt, 1);
          if (idx < CAP)
            list[idx] = ((unsigned long long)kh << 32) | (unsigned)(0x7fffffff - n);
        }
      }
    }
    __syncthreads();
    const int cnt = min(scnt, CAP);
    const int limit = min(cnt, need);
    for (int i = tid; i < cnt; i += 256) {       // rank selection, keys unique
      unsigned long long ki = list[i];
      int rank = 0;
      for (int j = 0; j < cnt; ++j) rank += (list[j] > ki);  // LDS broadcast
      if (rank < limit)
        sel_r[slotBase + rank] = 0x7fffffff - (int)(ki & 0xffffffffu);
    }
    __syncthreads();
    return limit;
  };

  // positives: top-64 of v >= 0.5, (v desc, index asc); emission == pick order
  // (f32 prio 1e9-rP tie-collapse + stable top_k keeps slot order).
  const int P = phase(true, NPOS, 0x3F000000u, 13, 0.5f, 3.0f, 0);
  // negatives fill slots P..255 (1e6-rN prios distinct in f32 -> pick order).
  phase(false, ROIBS - P, 0x40000000u, 11, 0.0f, 0.5f, P);

  // ===== emit (f32 output): thread tid == slot; covers all of d_out =====
  {
    const int r = sel_r[tid];
    const int isp = (tid < P) ? 1 : 0;
    const float4 rv = *(const float4*)(rois + ((size_t)b * NROI + r) * 4);
    float ry1 = rv.x, rx1 = rv.y, ry2 = rv.z, rx2 = rv.w;
    float best; int bj;
    roi_maxiou(cbox, carea, nv, ry1, rx1, ry2, rx2, best, bj);
    int label = isp ? ccls[bj] : BGCLS;

    float* out1 = out;                                    // [B,256,4]
    float* out2 = out + (size_t)BATCH * ROIBS * 4;        // [B,256,21]
    float* out3 = out + (size_t)BATCH * ROIBS * 25;       // [B,256,160]
    size_t row = (size_t)b * ROIBS + tid;

    *(float4*)(out1 + row * 4) = rv;                      // bit-exact roi copy

    float* o2 = out2 + row * 21;
    for (int c = 0; c <= BGCLS; ++c) o2[c] = (c == label) ? 1.0f : 0.0f;

    float t0 = 0.f, t1 = 0.f, t2 = 0.f, t3 = 0.f;
    if (isp) {
      const float eps = 1e-6f;
      float4 q = cbox[bj];
      float gy1 = q.x, gx1 = q.y, gy2 = q.z, gx2 = q.w;
      float rh = ry2 - ry1, rw = rx2 - rx1;
      float rcy = ry1 + rh * 0.5f, rcx = rx1 + rw * 0.5f;
      float gh = gy2 - gy1, gw = gx2 - gx1;
      float gcy = gy1 + gh * 0.5f, gcx = gx1 + gw * 0.5f;
      t0 = ((gcx - rcx) / (rw + eps)) * 10.0f;
      t1 = ((gcy - rcy) / (rh + eps)) * 10.0f;
      t2 = logf(fmaxf(gw, eps) / (rw + eps)) * 5.0f;
      t3 = logf(fmaxf(gh, eps) / (rh + eps)) * 5.0f;
    }
    int m0 = label * 4;                          // meaningful only when isp
    float* o3 = out3 + row * 160;
    for (int c = 0; c < 40; ++c) {               // 40 x 16B aligned vector stores
      float4 wv = make_float4(0.f, 0.f, 0.f, 0.f);
      if (isp) {
        float* wp = &wv.x;
#pragma unroll
        for (int jj = 0; jj < 4; ++jj) {
          int e = c * 4 + jj;
          float x = 0.f;
          if (e >= m0 && e < m0 + 4) x = 1.0f;   // mask4 half [0,80)
          int d = e - 80 - m0;                   // deltas half [80,160)
          if (d == 0) x = t0; else if (d == 1) x = t1;
          else if (d == 2) x = t2; else if (d == 3) x = t3;
          wp[jj] = x;
        }
      }
      *(float4*)(o3 + c * 4) = wv;
    }
  }
}

extern "C" void kernel_launch(void* const* d_in, const int* in_sizes, int n_in,
                              void* d_out, int out_size, void* d_ws, size_t ws_size,
                              hipStream_t stream) {
  const float* rois = (const float*)d_in[0];   // [32,12000,4] f32
  const int*   gtc  = (const int*)d_in[1];     // [32,200] i32
  const float* gtb  = (const float*)d_in[2];   // [32,200,4] f32
  float*       out  = (float*)d_out;           // f32, 32*256*185 elements

  size_t need = (size_t)BATCH * NROI * sizeof(float);
  if (d_ws && ws_size >= need) {
    float* mi = (float*)d_ws;
    k_ioumax<<<dim3((NROI + 255) / 256, BATCH), 256, 0, stream>>>(rois, gtc, gtb, mi);
    k_sel<true><<<BATCH, 256, 0, stream>>>(rois, gtc, gtb, mi, out);
  } else {
    k_sel<false><<<BATCH, 256, 0, stream>>>(rois, gtc, gtb, nullptr, out);
  }
}

// Round 9
// 100.683 us; speedup vs baseline: 5.3591x; 1.1557x over previous
//
#include <hip/hip_runtime.h>
#include <stdint.h>

// hipcc defaults to -ffp-contract=fast; FMA fusion perturbs IoU by ~1 ulp vs
// numpy and flips discrete selections (R3-R6 ladder). Force per-op IEEE f32.
#pragma clang fp contract(off)

#define BATCH 32
#define NROI  12000
#define NGT   200
#define BGCLS 20
#define ROIBS 256
#define NPOS  64
#define NBIN  1024
#define CAP   1024
#define NPAD  256        // padded compacted-GT slots (4 chunks of 64)
#define TSEL  1024       // k_sel block size
#define HSH   16         // histogram shards (lane-based)
#define HST   (NBIN + 2) // shard stride: same bin -> different banks/addresses

// Full-precision IoU over compacted valid GTs + first-max argmax (reference
// masked argmax). Bit-exact numpy f32: left-to-right ((ar+ag)-inter)+1e-8,
// IEEE div, no contraction. (Fallback/no-ws path only.)
__device__ __forceinline__ void roi_maxiou_all(const float4* cbox, const float* carea,
                                               int nv, float ry1, float rx1,
                                               float ry2, float rx2,
                                               float& best, int& bj) {
#pragma clang fp contract(off)
  float ar = (ry2 - ry1) * (rx2 - rx1);
  best = -1.0f; bj = 0;
  for (int j = 0; j < nv; ++j) {
    float4 q = cbox[j];
    float yy1 = fmaxf(ry1, q.x);
    float xx1 = fmaxf(rx1, q.y);
    float yy2 = fminf(ry2, q.z);
    float xx2 = fminf(rx2, q.w);
    float inter = fmaxf(yy2 - yy1, 0.0f) * fmaxf(xx2 - xx1, 0.0f);
    float den = ((ar + carea[j]) - inter) + 1e-8f;
    float iou = inter / den;
    if (iou > best) { best = iou; bj = j; }      // strict > == first-index argmax
  }
}

// Overlap-pruned max-IoU: ~84% of pairs have inter==0 exactly (iou=+0.0);
// the strict compare test (no rounding) is iff inter>0, so running the IEEE
// div only on overlapping pairs + the best<0 -> (+0.0, j=0) patch reproduces
// the reference max/argmax bit-exactly (zero ties -> first valid gt).
__global__ __launch_bounds__(256) void k_ioumax(const float* __restrict__ rois,
                                                const int* __restrict__ gtc,
                                                const float* __restrict__ gtb,
                                                float* __restrict__ max_iou,
                                                int* __restrict__ best_j) {
#pragma clang fp contract(off)
  __shared__ float4 cbox[NPAD];
  __shared__ float carea[NPAD];
  __shared__ int snv, wtmp[4];
  const int b = blockIdx.y;
  const int tid = threadIdx.x;

  // pad all slots with never-overlapping boxes, then compact valid gts in.
  cbox[tid] = make_float4(2.f, 2.f, 2.f, 2.f);
  carea[tid] = 0.f;
  {
    bool valid = false; float4 p = make_float4(0.f, 0.f, 0.f, 0.f);
    if (tid < NGT) {
      p = *(const float4*)(gtb + ((size_t)b * NGT + tid) * 4);
      valid = gtc[(size_t)b * NGT + tid] < BGCLS;
    }
    unsigned long long m = __ballot(valid);
    int w = tid >> 6;
    if ((tid & 63) == 0) wtmp[w] = __popcll(m);
    __syncthreads();                              // pad + wtmp complete
    if (tid == 0) snv = wtmp[0] + wtmp[1] + wtmp[2] + wtmp[3];
    if (valid) {
      int off = 0;
      for (int i = 0; i < w; ++i) off += wtmp[i];
      int pos = off + __popcll(m & ((1ull << (tid & 63)) - 1ull));
      cbox[pos] = p;
      carea[pos] = (p.z - p.x) * (p.w - p.y);
    }
    __syncthreads();
  }
  const int nv = snv;

  int n = blockIdx.x * 256 + tid;
  if (n >= NROI) return;
  const float4 r = *(const float4*)(rois + ((size_t)b * NROI + n) * 4);
  const float ar = (r.z - r.x) * (r.w - r.y);
  float best = -1.0f; int bj = 0;
#pragma unroll 1
  for (int c = 0; c < 4; ++c) {                   // static chunks: no scratch
    unsigned long long m = 0ull;
#pragma unroll 8
    for (int j2 = 0; j2 < 64; ++j2) {             // cheap exact overlap test
      float4 q = cbox[c * 64 + j2];
      bool ov = (fminf(r.z, q.z) > fmaxf(r.x, q.x)) &&
                (fminf(r.w, q.w) > fmaxf(r.y, q.y));
      m |= ((unsigned long long)ov) << j2;
    }
    while (m) {                                   // ascending j: first-max wins
      int j2 = __ffsll(m) - 1;
      m &= (m - 1);
      int j = c * 64 + j2;
      float4 q = cbox[j];
      float yy1 = fmaxf(r.x, q.x);
      float xx1 = fmaxf(r.y, q.y);
      float yy2 = fminf(r.z, q.z);
      float xx2 = fminf(r.w, q.w);
      float inter = fmaxf(yy2 - yy1, 0.0f) * fmaxf(xx2 - xx1, 0.0f);
      float den = ((ar + carea[j]) - inter) + 1e-8f;
      float iou = inter / den;
      if (iou > best) { best = iou; bj = j; }
    }
  }
  if (best < 0.0f && nv > 0) best = 0.0f;         // all-zero overlap case
  max_iou[(size_t)b * NROI + n] = best;
  best_j[(size_t)b * NROI + n] = bj;
}

// One 1024-thread block per image. Two top-k phases (pos v>=0.5 by bits(v);
// neg 0<=v<0.5 by bits(f32(v+2.0)) -- the +2.0 ROUNDING merges nearby ious,
// merged ties break asc-index). key = kh<<32 | (0x7fffffff-n): desc ==
// (val desc, idx asc) == jax stable top_k. Histogram-prune (lane-sharded,
// parallel suffix-scan threshold) + rank selection (keys unique).
template <bool USE_WS>
__global__ __launch_bounds__(TSEL) void k_sel(const float* __restrict__ rois,
                                              const int* __restrict__ gtc,
                                              const float* __restrict__ gtb,
                                              const float* __restrict__ max_iou,
                                              const int* __restrict__ best_j,
                                              float* __restrict__ out) {
#pragma clang fp contract(off)
  __shared__ float4 cbox[NGT];
  __shared__ float carea[NGT];
  __shared__ int ccls[NGT];
  __shared__ int snv, wtmp[16];
  __shared__ float val[NROI];
  __shared__ unsigned long long list[CAP];
  __shared__ int hs[HSH][HST];
  __shared__ int ss[NBIN];
  __shared__ int sel_r[ROIBS];
  __shared__ int scnt, sT;
  const int b = blockIdx.x;
  const int tid = threadIdx.x;

  {
    bool valid = false; float4 p = make_float4(0.f, 0.f, 0.f, 0.f); int cls = BGCLS;
    if (tid < NGT) {
      p = *(const float4*)(gtb + ((size_t)b * NGT + tid) * 4);
      cls = gtc[(size_t)b * NGT + tid];
      valid = (cls < BGCLS);
    }
    unsigned long long m = __ballot(valid);
    int w = tid >> 6;
    if ((tid & 63) == 0) wtmp[w] = __popcll(m);
    if (tid < ROIBS) sel_r[tid] = 0;             // default roi (slot underflow)
    __syncthreads();
    if (tid == 0) { int s = 0; for (int i = 0; i < 16; ++i) s += wtmp[i]; snv = s; }
    if (valid) {
      int off = 0;
      for (int i = 0; i < w; ++i) off += wtmp[i];
      int pos = off + __popcll(m & ((1ull << (tid & 63)) - 1ull));
      cbox[pos] = p;
      carea[pos] = (p.z - p.x) * (p.w - p.y);
      ccls[pos] = cls;
    }
    __syncthreads();
  }
  const int nv = snv;

  if constexpr (USE_WS) {
    for (int n = tid; n < NROI; n += TSEL) val[n] = max_iou[(size_t)b * NROI + n];
  } else {
    for (int n = tid; n < NROI; n += TSEL) {
      const float4 r = *(const float4*)(rois + ((size_t)b * NROI + n) * 4);
      float best; int bj;
      roi_maxiou_all(cbox, carea, nv, r.x, r.y, r.z, r.w, best, bj);
      val[n] = best;
    }
  }
  __syncthreads();

  // One phase: filter [lo,hi), key kh = bits(isPos ? v : v+2.0f), bin
  // monotone in key (equal keys -> equal bin). T = highest bin with
  // suffix >= need; candidates (bin>=T) ranked desc -> slots. Returns #filled.
  auto phase = [&](bool isPos, int need, unsigned base, int shift,
                   float lo, float hi, int slotBase) -> int {
    for (int i = tid; i < HSH * HST; i += TSEL) ((int*)hs)[i] = 0;
    if (tid == 0) { scnt = 0; sT = 0; }
    __syncthreads();
    const int sh = tid & (HSH - 1);              // lane-based: same bin ->
    for (int n = tid; n < NROI; n += TSEL) {     // 16 banks, 16 addresses
      float v = val[n];
      if (v >= lo && v < hi) {
        float kv = isPos ? v : (v + 2.0f);       // IEEE RNE, no contraction
        int bin = min((int)((__float_as_uint(kv) - base) >> shift), NBIN - 1);
        atomicAdd(&hs[sh][bin], 1);
      }
    }
    __syncthreads();
    {                                            // per-bin totals (1 bin/thread)
      int s = 0;
#pragma unroll
      for (int i = 0; i < HSH; ++i) s += hs[i][tid];
      ss[tid] = s;
    }
    __syncthreads();
    for (int off = 1; off < NBIN; off <<= 1) {   // Hillis-Steele suffix scan
      int a = (tid + off < NBIN) ? ss[tid + off] : 0;
      __syncthreads();
      ss[tid] += a;
      __syncthreads();
    }
    {                                            // unique crossing -> T
      int nxt = (tid + 1 < NBIN) ? ss[tid + 1] : 0;
      if (ss[tid] >= need && nxt < need) sT = tid;
    }
    __syncthreads();
    const int T = sT;                            // 0 if total < need (take all)
    for (int n = tid; n < NROI; n += TSEL) {
      float v = val[n];
      if (v >= lo && v < hi) {
        unsigned kh = __float_as_uint(isPos ? v : (v + 2.0f));
        int bin = min((int)((kh - base) >> shift), NBIN - 1);
        if (bin >= T) {
          int idx = atomicAdd(&scnt, 1);
          if (idx < CAP)
            list[idx] = ((unsigned long long)kh << 32) | (unsigned)(0x7fffffff - n);
        }
      }
    }
    __syncthreads();
    const int cnt = min(scnt, CAP);
    const int limit = min(cnt, need);
    if (tid < cnt) {                             // rank selection, keys unique
      unsigned long long ki = list[tid];
      int rank = 0;
      for (int j = 0; j < cnt; ++j) rank += (list[j] > ki);  // LDS broadcast
      if (rank < limit)
        sel_r[slotBase + rank] = 0x7fffffff - (int)(ki & 0xffffffffu);
    }
    __syncthreads();
    return limit;
  };

  // positives: top-64 of v >= 0.5; emission == pick order (f32 prio 1e9-rP
  // tie-collapse + stable top_k keeps slot order). negatives fill P..255.
  const int P = phase(true, NPOS, 0x3F000000u, 13, 0.5f, 3.0f, 0);
  phase(false, ROIBS - P, 0x40000000u, 11, 0.0f, 0.5f, P);

  // ===== emit (f32 output): 4 threads per slot; covers all of d_out =====
  {
    const int slot = tid >> 2, q = tid & 3;
    const int r = sel_r[slot];
    const int isp = (slot < P) ? 1 : 0;
    const float4 rv = *(const float4*)(rois + ((size_t)b * NROI + r) * 4);
    float ry1 = rv.x, rx1 = rv.y, ry2 = rv.z, rx2 = rv.w;
    int bj;
    if constexpr (USE_WS) {
      bj = best_j[(size_t)b * NROI + r];
    } else {
      float bb;
      roi_maxiou_all(cbox, carea, nv, ry1, rx1, ry2, rx2, bb, bj);
    }
    int label = isp ? ccls[bj] : BGCLS;

    float* out1 = out;                                    // [B,256,4]
    float* out2 = out + (size_t)BATCH * ROIBS * 4;        // [B,256,21]
    float* out3 = out + (size_t)BATCH * ROIBS * 25;       // [B,256,160]
    size_t row = (size_t)b * ROIBS + slot;

    if (q == 0) {
      *(float4*)(out1 + row * 4) = rv;                    // bit-exact roi copy
      float* o2 = out2 + row * 21;
      for (int c = 0; c <= BGCLS; ++c) o2[c] = (c == label) ? 1.0f : 0.0f;
    }

    float t0 = 0.f, t1 = 0.f, t2 = 0.f, t3 = 0.f;
    if (isp) {
      const float eps = 1e-6f;
      float4 g = cbox[bj];
      float gy1 = g.x, gx1 = g.y, gy2 = g.z, gx2 = g.w;
      float rh = ry2 - ry1, rw = rx2 - rx1;
      float rcy = ry1 + rh * 0.5f, rcx = rx1 + rw * 0.5f;
      float gh = gy2 - gy1, gw = gx2 - gx1;
      float gcy = gy1 + gh * 0.5f, gcx = gx1 + gw * 0.5f;
      t0 = ((gcx - rcx) / (rw + eps)) * 10.0f;
      t1 = ((gcy - rcy) / (rh + eps)) * 10.0f;
      t2 = logf(fmaxf(gw, eps) / (rw + eps)) * 5.0f;
      t3 = logf(fmaxf(gh, eps) / (rh + eps)) * 5.0f;
    }
    int m0 = label * 4;                          // meaningful only when isp
    float* o3 = out3 + row * 160;
    for (int c = q * 10; c < q * 10 + 10; ++c) { // 10 x 16B stores per thread
      float4 wv = make_float4(0.f, 0.f, 0.f, 0.f);
      if (isp) {
        float* wp = &wv.x;
#pragma unroll
        for (int jj = 0; jj < 4; ++jj) {
          int e = c * 4 + jj;
          float x = 0.f;
          if (e >= m0 && e < m0 + 4) x = 1.0f;   // mask4 half [0,80)
          int d = e - 80 - m0;                   // deltas half [80,160)
          if (d == 0) x = t0; else if (d == 1) x = t1;
          else if (d == 2) x = t2; else if (d == 3) x = t3;
          wp[jj] = x;
        }
      }
      *(float4*)(o3 + c * 4) = wv;
    }
  }
}

extern "C" void kernel_launch(void* const* d_in, const int* in_sizes, int n_in,
                              void* d_out, int out_size, void* d_ws, size_t ws_size,
                              hipStream_t stream) {
  const float* rois = (const float*)d_in[0];   // [32,12000,4] f32
  const int*   gtc  = (const int*)d_in[1];     // [32,200] i32
  const float* gtb  = (const float*)d_in[2];   // [32,200,4] f32
  float*       out  = (float*)d_out;           // f32, 32*256*185 elements

  size_t need = (size_t)BATCH * NROI * 8;      // f32 max_iou + i32 best_j
  if (d_ws && ws_size >= need) {
    float* mi = (float*)d_ws;
    int*   bj = (int*)d_ws + (size_t)BATCH * NROI;
    k_ioumax<<<dim3((NROI + 255) / 256, BATCH), 256, 0, stream>>>(rois, gtc, gtb, mi, bj);
    k_sel<true><<<BATCH, TSEL, 0, stream>>>(rois, gtc, gtb, mi, bj, out);
  } else {
    k_sel<false><<<BATCH, TSEL, 0, stream>>>(rois, gtc, gtb, nullptr, nullptr, out);
  }
}

// Round 10
// 86.334 us; speedup vs baseline: 6.2498x; 1.1662x over previous
//
#include <hip/hip_runtime.h>
#include <stdint.h>

// hipcc defaults to -ffp-contract=fast; FMA fusion perturbs IoU by ~1 ulp vs
// numpy and flips discrete selections (R3-R6 ladder). Force per-op IEEE f32.
#pragma clang fp contract(off)

#define BATCH 32
#define NROI  12000
#define NGT   200
#define BGCLS 20
#define ROIBS 256
#define NPOS  64
#define NBIN  1024
#define CAP   1024
#define TSEL  1024       // k_sel block size
#define HSH   16         // histogram shards (lane-based)
#define HST   (NBIN + 2) // shard stride: same bin -> different banks/addresses

// Exact reference IoU max/argmax over compacted valid GTs (first-max wins).
// Bit-exact numpy f32: left-to-right ((ar+ag)-inter)+1e-8, IEEE div.
__device__ __forceinline__ void roi_maxiou_all(const float4* cbox, const float* carea,
                                               int nv, float ry1, float rx1,
                                               float ry2, float rx2,
                                               float& best, int& bj) {
#pragma clang fp contract(off)
  float ar = (ry2 - ry1) * (rx2 - rx1);
  best = -1.0f; bj = 0;
  for (int j = 0; j < nv; ++j) {
    float4 q = cbox[j];
    float yy1 = fmaxf(ry1, q.x);
    float xx1 = fmaxf(rx1, q.y);
    float yy2 = fminf(ry2, q.z);
    float xx2 = fminf(rx2, q.w);
    float inter = fmaxf(yy2 - yy1, 0.0f) * fmaxf(xx2 - xx1, 0.0f);
    float den = ((ar + carea[j]) - inter) + 1e-8f;
    float iou = inter / den;
    if (iou > best) { best = iou; bj = j; }      // strict > == first-index argmax
  }
}

// Fast path: approx iou = inter * v_rcp(den) (~2 ulp). Track top-2 approx +
// argmax. If winner leads by > margin (32 ulp), it is provably the exact f32
// argmax -> compute the exact IEEE IoU for that single j (bit-exact value).
// Near-ties / degenerate cases (P ~ 1e-4) take the exact full-loop fallback.
__global__ __launch_bounds__(256) void k_ioumax(const float* __restrict__ rois,
                                                const int* __restrict__ gtc,
                                                const float* __restrict__ gtb,
                                                float* __restrict__ max_iou,
                                                int* __restrict__ best_j) {
#pragma clang fp contract(off)
  __shared__ float4 cbox[NGT];
  __shared__ float carea[NGT];
  __shared__ int snv, wtmp[4];
  const int b = blockIdx.y;
  const int tid = threadIdx.x;

  {                                              // order-preserving compaction
    bool valid = false; float4 p = make_float4(0.f, 0.f, 0.f, 0.f);
    if (tid < NGT) {
      p = *(const float4*)(gtb + ((size_t)b * NGT + tid) * 4);
      valid = gtc[(size_t)b * NGT + tid] < BGCLS;
    }
    unsigned long long m = __ballot(valid);
    int w = tid >> 6;
    if ((tid & 63) == 0) wtmp[w] = __popcll(m);
    __syncthreads();
    if (tid == 0) snv = wtmp[0] + wtmp[1] + wtmp[2] + wtmp[3];
    if (valid) {
      int off = 0;
      for (int i = 0; i < w; ++i) off += wtmp[i];
      int pos = off + __popcll(m & ((1ull << (tid & 63)) - 1ull));
      cbox[pos] = p;
      carea[pos] = (p.z - p.x) * (p.w - p.y);
    }
    __syncthreads();
  }
  const int nv = snv;

  int n = blockIdx.x * 256 + tid;
  if (n >= NROI) return;
  const float4 r = *(const float4*)(rois + ((size_t)b * NROI + n) * 4);
  const float ar = (r.z - r.x) * (r.w - r.y);

  float best; int bj;
  if (nv == 0) {
    best = -1.0f; bj = 0;                        // never occurs for this data
  } else {
    float v1 = -1.0f, v2 = -2.0f; int j1 = 0;
#pragma unroll 2
    for (int j = 0; j < nv; ++j) {               // uniform loop, no divergence
      float4 q = cbox[j];
      float ag = carea[j];
      float yy1 = fmaxf(r.x, q.x);
      float xx1 = fmaxf(r.y, q.y);
      float yy2 = fminf(r.z, q.z);
      float xx2 = fminf(r.w, q.w);
      float inter = fmaxf(yy2 - yy1, 0.0f) * fmaxf(xx2 - xx1, 0.0f);
      float den = ((ar + ag) - inter) + 1e-8f;
      float a = inter * __builtin_amdgcn_rcpf(den);
      bool gt = a > v1;                          // strict > : ties keep first j
      v2 = gt ? v1 : fmaxf(v2, a);               // second-best approx
      j1 = gt ? j : j1;
      v1 = gt ? a : v1;
    }
    if (v2 >= v1 * 0.999995f) {                  // near-tie -> exact fallback
      roi_maxiou_all(cbox, carea, nv, r.x, r.y, r.z, r.w, best, bj);
    } else {                                     // unique winner: exact value
      float4 q = cbox[j1];
      float yy1 = fmaxf(r.x, q.x);
      float xx1 = fmaxf(r.y, q.y);
      float yy2 = fminf(r.z, q.z);
      float xx2 = fminf(r.w, q.w);
      float inter = fmaxf(yy2 - yy1, 0.0f) * fmaxf(xx2 - xx1, 0.0f);
      float den = ((ar + carea[j1]) - inter) + 1e-8f;
      best = inter / den;                        // IEEE f32 div, bit-exact
      bj = j1;
    }
  }
  max_iou[(size_t)b * NROI + n] = best;
  best_j[(size_t)b * NROI + n] = bj;
}

// One 1024-thread block per image. Two top-k phases (pos v>=0.5 by bits(v);
// neg 0<=v<0.5 by bits(f32(v+2.0)) -- the +2.0 ROUNDING merges nearby ious,
// merged ties break asc-index). key = kh<<32 | (0x7fffffff-n): desc ==
// (val desc, idx asc) == jax stable top_k. Histogram-prune (lane-sharded,
// wave-shuffle suffix-scan threshold) + rank selection (keys unique).
template <bool USE_WS>
__global__ __launch_bounds__(TSEL) void k_sel(const float* __restrict__ rois,
                                              const int* __restrict__ gtc,
                                              const float* __restrict__ gtb,
                                              const float* __restrict__ max_iou,
                                              const int* __restrict__ best_j,
                                              float* __restrict__ out) {
#pragma clang fp contract(off)
  __shared__ float4 cbox[NGT];
  __shared__ float carea[NGT];
  __shared__ int ccls[NGT];
  __shared__ int snv, wtmp[16];
  __shared__ int wtot[16], wnext[16];
  __shared__ float val[NROI];
  __shared__ unsigned long long list[CAP];
  __shared__ int hs[HSH][HST];
  __shared__ int ss[NBIN];
  __shared__ int sel_r[ROIBS];
  __shared__ int scnt, sT;
  const int b = blockIdx.x;
  const int tid = threadIdx.x;

  {                                              // order-preserving compaction
    bool valid = false; float4 p = make_float4(0.f, 0.f, 0.f, 0.f); int cls = BGCLS;
    if (tid < NGT) {
      p = *(const float4*)(gtb + ((size_t)b * NGT + tid) * 4);
      cls = gtc[(size_t)b * NGT + tid];
      valid = (cls < BGCLS);
    }
    unsigned long long m = __ballot(valid);
    int w = tid >> 6;
    if ((tid & 63) == 0) wtmp[w] = __popcll(m);
    if (tid < ROIBS) sel_r[tid] = 0;             // default roi (slot underflow)
    __syncthreads();
    if (tid == 0) { int s = 0; for (int i = 0; i < 16; ++i) s += wtmp[i]; snv = s; }
    if (valid) {
      int off = 0;
      for (int i = 0; i < w; ++i) off += wtmp[i];
      int pos = off + __popcll(m & ((1ull << (tid & 63)) - 1ull));
      cbox[pos] = p;
      carea[pos] = (p.z - p.x) * (p.w - p.y);
      ccls[pos] = cls;
    }
    __syncthreads();
  }
  const int nv = snv;

  if constexpr (USE_WS) {
    for (int n = tid; n < NROI; n += TSEL) val[n] = max_iou[(size_t)b * NROI + n];
  } else {
    for (int n = tid; n < NROI; n += TSEL) {
      const float4 r = *(const float4*)(rois + ((size_t)b * NROI + n) * 4);
      float best; int bj;
      roi_maxiou_all(cbox, carea, nv, r.x, r.y, r.z, r.w, best, bj);
      val[n] = best;
    }
  }
  __syncthreads();

  // One phase: filter [lo,hi), key kh = bits(isPos ? v : v+2.0f), bin
  // monotone in key (equal keys -> equal bin). T = highest bin with
  // suffix >= need; candidates (bin>=T) ranked desc -> slots. Returns #filled.
  auto phase = [&](bool isPos, int need, unsigned base, int shift,
                   float lo, float hi, int slotBase) -> int {
    for (int i = tid; i < HSH * HST; i += TSEL) ((int*)hs)[i] = 0;
    if (tid == 0) { scnt = 0; sT = 0; }
    __syncthreads();
    const int sh = tid & (HSH - 1);              // lane-based: same bin ->
    for (int n = tid; n < NROI; n += TSEL) {     // 16 banks, 16 addresses
      float v = val[n];
      if (v >= lo && v < hi) {
        float kv = isPos ? v : (v + 2.0f);       // IEEE RNE, no contraction
        int bin = min((int)((__float_as_uint(kv) - base) >> shift), NBIN - 1);
        atomicAdd(&hs[sh][bin], 1);
      }
    }
    __syncthreads();
    // suffix scan over 1024 bins: wave shuffle scan + 16-wave combine
    int cnt_bin = 0;
#pragma unroll
    for (int i = 0; i < HSH; ++i) cnt_bin += hs[i][tid];
    const int lane = tid & 63, w = tid >> 6;
    int sfx = cnt_bin;                           // per-wave suffix (bins desc)
#pragma unroll
    for (int off = 1; off < 64; off <<= 1) {
      int t = __shfl_down(sfx, off, 64);
      sfx += (lane + off < 64) ? t : 0;
    }
    if (lane == 0) wtot[w] = sfx;                // wave total (lane0 = full)
    __syncthreads();
    if (tid < 16) {
      int s = 0;
      for (int i = tid + 1; i < 16; ++i) s += wtot[i];
      wnext[tid] = s;                            // sum over waves after w
    }
    __syncthreads();
    const int suffix = sfx + wnext[w];           // total over bins >= tid
    ss[tid] = suffix;
    __syncthreads();
    {
      int nxt = (tid + 1 < NBIN) ? ss[tid + 1] : 0;
      if (suffix >= need && nxt < need) sT = tid;
    }
    __syncthreads();
    const int T = sT;                            // 0 if total < need (take all)
    for (int n = tid; n < NROI; n += TSEL) {
      float v = val[n];
      if (v >= lo && v < hi) {
        unsigned kh = __float_as_uint(isPos ? v : (v + 2.0f));
        int bin = min((int)((kh - base) >> shift), NBIN - 1);
        if (bin >= T) {
          int idx = atomicAdd(&scnt, 1);
          if (idx < CAP)
            list[idx] = ((unsigned long long)kh << 32) | (unsigned)(0x7fffffff - n);
        }
      }
    }
    __syncthreads();
    const int cnt = min(scnt, CAP);
    const int limit = min(cnt, need);
    if (tid < cnt) {                             // rank selection, keys unique
      unsigned long long ki = list[tid];
      int rank = 0;
      for (int j = 0; j < cnt; ++j) rank += (list[j] > ki);  // LDS broadcast
      if (rank < limit)
        sel_r[slotBase + rank] = 0x7fffffff - (int)(ki & 0xffffffffu);
    }
    __syncthreads();
    return limit;
  };

  // positives: top-64 of v >= 0.5; emission == pick order (f32 prio 1e9-rP
  // tie-collapse + stable top_k keeps slot order). negatives fill P..255.
  const int P = phase(true, NPOS, 0x3F000000u, 13, 0.5f, 3.0f, 0);
  phase(false, ROIBS - P, 0x40000000u, 11, 0.0f, 0.5f, P);

  // ===== emit (f32 output): 4 threads per slot; covers all of d_out =====
  {
    const int slot = tid >> 2, q = tid & 3;
    const int r = sel_r[slot];
    const int isp = (slot < P) ? 1 : 0;
    const float4 rv = *(const float4*)(rois + ((size_t)b * NROI + r) * 4);
    float ry1 = rv.x, rx1 = rv.y, ry2 = rv.z, rx2 = rv.w;
    int bj;
    if constexpr (USE_WS) {
      bj = best_j[(size_t)b * NROI + r];
    } else {
      float bb;
      roi_maxiou_all(cbox, carea, nv, ry1, rx1, ry2, rx2, bb, bj);
    }
    int label = isp ? ccls[bj] : BGCLS;

    float* out1 = out;                                    // [B,256,4]
    float* out2 = out + (size_t)BATCH * ROIBS * 4;        // [B,256,21]
    float* out3 = out + (size_t)BATCH * ROIBS * 25;       // [B,256,160]
    size_t row = (size_t)b * ROIBS + slot;

    if (q == 0) {
      *(float4*)(out1 + row * 4) = rv;                    // bit-exact roi copy
      float* o2 = out2 + row * 21;
      for (int c = 0; c <= BGCLS; ++c) o2[c] = (c == label) ? 1.0f : 0.0f;
    }

    float t0 = 0.f, t1 = 0.f, t2 = 0.f, t3 = 0.f;
    if (isp) {
      const float eps = 1e-6f;
      float4 g = cbox[bj];
      float gy1 = g.x, gx1 = g.y, gy2 = g.z, gx2 = g.w;
      float rh = ry2 - ry1, rw = rx2 - rx1;
      float rcy = ry1 + rh * 0.5f, rcx = rx1 + rw * 0.5f;
      float gh = gy2 - gy1, gw = gx2 - gx1;
      float gcy = gy1 + gh * 0.5f, gcx = gx1 + gw * 0.5f;
      t0 = ((gcx - rcx) / (rw + eps)) * 10.0f;
      t1 = ((gcy - rcy) / (rh + eps)) * 10.0f;
      t2 = logf(fmaxf(gw, eps) / (rw + eps)) * 5.0f;
      t3 = logf(fmaxf(gh, eps) / (rh + eps)) * 5.0f;
    }
    int m0 = label * 4;                          // meaningful only when isp
    float* o3 = out3 + row * 160;
    for (int c = q * 10; c < q * 10 + 10; ++c) { // 10 x 16B stores per thread
      float4 wv = make_float4(0.f, 0.f, 0.f, 0.f);
      if (isp) {
        float* wp = &wv.x;
#pragma unroll
        for (int jj = 0; jj < 4; ++jj) {
          int e = c * 4 + jj;
          float x = 0.f;
          if (e >= m0 && e < m0 + 4) x = 1.0f;   // mask4 half [0,80)
          int d = e - 80 - m0;                   // deltas half [80,160)
          if (d == 0) x = t0; else if (d == 1) x = t1;
          else if (d == 2) x = t2; else if (d == 3) x = t3;
          wp[jj] = x;
        }
      }
      *(float4*)(o3 + c * 4) = wv;
    }
  }
}

extern "C" void kernel_launch(void* const* d_in, const int* in_sizes, int n_in,
                              void* d_out, int out_size, void* d_ws, size_t ws_size,
                              hipStream_t stream) {
  const float* rois = (const float*)d_in[0];   // [32,12000,4] f32
  const int*   gtc  = (const int*)d_in[1];     // [32,200] i32
  const float* gtb  = (const float*)d_in[2];   // [32,200,4] f32
  float*       out  = (float*)d_out;           // f32, 32*256*185 elements

  size_t need = (size_t)BATCH * NROI * 8;      // f32 max_iou + i32 best_j
  if (d_ws && ws_size >= need) {
    float* mi = (float*)d_ws;
    int*   bj = (int*)d_ws + (size_t)BATCH * NROI;
    k_ioumax<<<dim3((NROI + 255) / 256, BATCH), 256, 0, stream>>>(rois, gtc, gtb, mi, bj);
    k_sel<true><<<BATCH, TSEL, 0, stream>>>(rois, gtc, gtb, mi, bj, out);
  } else {
    k_sel<false><<<BATCH, TSEL, 0, stream>>>(rois, gtc, gtb, nullptr, nullptr, out);
  }
}